// Round 3
// baseline (4956.184 us; speedup 1.0000x reference)
//
#include <hip/hip_runtime.h>

#define BB 1024
#define TT 512
#define HH 64
#define NB 2   // batch elements per block

__device__ __forceinline__ float sigmoidf_(float v) {
    return 1.0f / (1.0f + __expf(-v));
}
__device__ __forceinline__ float tanhf_(float v) {
    // tanh(x) = 2*sigmoid(2x) - 1  (safe: no inf/inf)
    return fmaf(2.0f, sigmoidf_(2.0f * v), -1.0f);
}

// Layer-pipelined fused LSTM, K-split by 2 to keep weights register-resident.
// 512 threads: thread (g = t>>1, half = t&1) owns K-half `half` of gate row g.
// Weight regs/thread = 3 rows x 32 floats = 96 VGPRs (fits under the 128 cap
// needed for 16 waves/CU). Adjacent-lane halves combine via __shfl_xor(.,1).
// Layer 1 runs one timestep behind layer 0 (2 barriers/iter).
__global__ __launch_bounds__(512, 4)
void lstm_fused3(const float* __restrict__ x,     // [B,T] (I=1)
                 const float* __restrict__ Wih0,  // [256]
                 const float* __restrict__ Whh0,  // [256,64]
                 const float* __restrict__ bih0,  // [256]
                 const float* __restrict__ bhh0,  // [256]
                 const float* __restrict__ Wih1,  // [256,64]
                 const float* __restrict__ Whh1,  // [256,64]
                 const float* __restrict__ bih1,  // [256]
                 const float* __restrict__ bhh1,  // [256]
                 const float* __restrict__ Wfc,   // [64]
                 const float* __restrict__ bfc,   // [1]
                 float* __restrict__ out)         // [B]
{
    __shared__ float s_x[NB][TT];
    __shared__ float s_h0[NB][HH];
    __shared__ float s_h1[NB][HH];
    __shared__ float s_g0[NB][256];
    __shared__ float s_g1[NB][256];

    const int t    = threadIdx.x;
    const int g    = t >> 1;        // gate row 0..255
    const int half = t & 1;         // K-half 0/1
    const int b0   = blockIdx.x * NB;

    // ---- one-time: per-thread constants + half weight rows into registers ----
    const float xw0   = Wih0[g];
    const float bias0 = bih0[g] + bhh0[g];
    const float bias1 = bih1[g] + bhh1[g];

    float4 w0[8], wi1[8], w1[8];
    {
        const float4* p0 = (const float4*)(Whh0 + g * HH + half * 32);
        const float4* p1 = (const float4*)(Wih1 + g * HH + half * 32);
        const float4* p2 = (const float4*)(Whh1 + g * HH + half * 32);
#pragma unroll
        for (int i = 0; i < 8; ++i) {
            w0[i]  = p0[i];
            wi1[i] = p1[i];
            w1[i]  = p2[i];
        }
    }

    // stage x rows (coalesced): NB*TT = 1024 floats / 512 threads = 2 each
#pragma unroll
    for (int k = 0; k < (NB * TT) / 512; ++k) {
        int idx = t + 512 * k;
        int nb  = idx >> 9;      // / TT
        int pos = idx & (TT - 1);
        s_x[nb][pos] = x[(b0 + nb) * TT + pos];
    }

    // zero initial hidden state (NB*HH = 128 floats per array)
    if (t < NB * HH) {
        (&s_h0[0][0])[t] = 0.0f;
        (&s_h1[0][0])[t] = 0.0f;
    }

    // cell state residency (threads 0..255):
    //   t<128  -> layer0 (nb=t>>6, j=t&63)
    //   128..255 -> layer1 (nb=(t>>6)&1, j=t&63)
    float cst = 0.0f;

    __syncthreads();

    for (int s = 0; s <= TT; ++s) {
        // ---- phase 1 (all 512 threads): half dot-products, both layers ----
        // layer0 gates for timestep s (h0[s-1]); layer1 gates for timestep
        // s-1 (h1[s-2] recurrent + h0[s-1] input).
        {
            const int xs = (s < TT) ? s : (TT - 1);  // s==TT result discarded
            float acc0[NB], acc1[NB];
#pragma unroll
            for (int nb = 0; nb < NB; ++nb) {
                acc0[nb] = (half == 0) ? fmaf(xw0, s_x[nb][xs], bias0) : 0.0f;
                acc1[nb] = (half == 0) ? bias1 : 0.0f;
            }
#pragma unroll
            for (int i = 0; i < 8; ++i) {
#pragma unroll
                for (int nb = 0; nb < NB; ++nb) {
                    const float4 h0q = ((const float4*)s_h0[nb])[half * 8 + i];
                    const float4 h1q = ((const float4*)s_h1[nb])[half * 8 + i];
                    acc0[nb] = fmaf(w0[i].x,  h0q.x, acc0[nb]);
                    acc0[nb] = fmaf(w0[i].y,  h0q.y, acc0[nb]);
                    acc0[nb] = fmaf(w0[i].z,  h0q.z, acc0[nb]);
                    acc0[nb] = fmaf(w0[i].w,  h0q.w, acc0[nb]);
                    acc1[nb] = fmaf(wi1[i].x, h0q.x, acc1[nb]);
                    acc1[nb] = fmaf(wi1[i].y, h0q.y, acc1[nb]);
                    acc1[nb] = fmaf(wi1[i].z, h0q.z, acc1[nb]);
                    acc1[nb] = fmaf(wi1[i].w, h0q.w, acc1[nb]);
                    acc1[nb] = fmaf(w1[i].x,  h1q.x, acc1[nb]);
                    acc1[nb] = fmaf(w1[i].y,  h1q.y, acc1[nb]);
                    acc1[nb] = fmaf(w1[i].z,  h1q.z, acc1[nb]);
                    acc1[nb] = fmaf(w1[i].w,  h1q.w, acc1[nb]);
                }
            }
            // combine K-halves across adjacent lanes; even lane writes g0,
            // odd lane writes g1 (both lanes hold full sums after xor).
#pragma unroll
            for (int nb = 0; nb < NB; ++nb) {
                float o0 = acc0[nb] + __shfl_xor(acc0[nb], 1, 64);
                float o1 = acc1[nb] + __shfl_xor(acc1[nb], 1, 64);
                if (half == 0) s_g0[nb][g] = o0;
                else           s_g1[nb][g] = o1;
            }
        }
        __syncthreads();

        // ---- phase 2: unit updates on threads 0..255 ----
        if (t < 128) {
            // layer 0, timestep s (skip at s==TT)
            if (s < TT) {
                const int nb = t >> 6;
                const int j  = t & 63;
                float i_ = sigmoidf_(s_g0[nb][j]);
                float f_ = sigmoidf_(s_g0[nb][j + 64]);
                float g_ = tanhf_(s_g0[nb][j + 128]);
                float o_ = sigmoidf_(s_g0[nb][j + 192]);
                cst = fmaf(f_, cst, i_ * g_);
                s_h0[nb][j] = o_ * tanhf_(cst);
            }
        } else if (t < 256) {
            // layer 1, timestep s-1 (skip at s==0)
            if (s >= 1) {
                const int nb = (t >> 6) & 1;
                const int j  = t & 63;
                float i_ = sigmoidf_(s_g1[nb][j]);
                float f_ = sigmoidf_(s_g1[nb][j + 64]);
                float g_ = tanhf_(s_g1[nb][j + 128]);
                float o_ = sigmoidf_(s_g1[nb][j + 192]);
                cst = fmaf(f_, cst, i_ * g_);
                s_h1[nb][j] = o_ * tanhf_(cst);
            }
        }
        __syncthreads();
    }

    // ---- epilogue: out[b0+nb] = h1_last . Wfc + bfc ----
    if (t < NB * HH) {
        const int nb = t >> 6;
        const int j  = t & 63;
        float v = s_h1[nb][j] * Wfc[j];
#pragma unroll
        for (int off = 32; off > 0; off >>= 1) {
            v += __shfl_down(v, off);
        }
        if (j == 0) out[b0 + nb] = v + bfc[0];
    }
}

extern "C" void kernel_launch(void* const* d_in, const int* in_sizes, int n_in,
                              void* d_out, int out_size, void* d_ws, size_t ws_size,
                              hipStream_t stream) {
    const float* x    = (const float*)d_in[0];
    const float* Wih0 = (const float*)d_in[1];
    const float* Whh0 = (const float*)d_in[2];
    const float* bih0 = (const float*)d_in[3];
    const float* bhh0 = (const float*)d_in[4];
    const float* Wih1 = (const float*)d_in[5];
    const float* Whh1 = (const float*)d_in[6];
    const float* bih1 = (const float*)d_in[7];
    const float* bhh1 = (const float*)d_in[8];
    const float* Wfc  = (const float*)d_in[9];
    const float* bfc  = (const float*)d_in[10];
    float* out = (float*)d_out;

    lstm_fused3<<<dim3(BB / NB), dim3(512), 0, stream>>>(
        x, Wih0, Whh0, bih0, bhh0, Wih1, Whh1, bih1, bhh1, Wfc, bfc, out);
}

// Round 4
// 1710.793 us; speedup vs baseline: 2.8970x; 2.8970x over previous
//
#include <hip/hip_runtime.h>

#define BB 1024
#define TT 512
#define HH 64
#define NB 4   // batch elements per block; grid = 1024/4 = 256 = one block per CU

__device__ __forceinline__ float sigmoidf_(float v) {
    return 1.0f / (1.0f + __expf(-v));
}
__device__ __forceinline__ float tanhf_(float v) {
    // tanh(x) = 2*sigmoid(2x) - 1  (safe: no inf/inf)
    return fmaf(2.0f, sigmoidf_(2.0f * v), -1.0f);
}

// Layer-pipelined fused LSTM, weights fully register-resident.
// 256 threads, thread g owns gate-row g of all three matvecs (Whh0, Wih1,
// Whh1): 192 weight VGPRs. amdgpu_waves_per_eu(1,1) pins the allocator to a
// 512-reg budget so it cannot spill weights for occupancy (R2/R3 post-mortem:
// the allocator ignores __launch_bounds__ and spills to chase waves).
// Layer 1 runs one timestep behind layer 0: one compute phase + one update
// phase = 2 barriers/iter. NB=4 batches/block -> grid 256 = 1 block/CU,
// single dispatch round; update phase occupies all 256 threads (2 units each).
__global__ __launch_bounds__(256)
__attribute__((amdgpu_waves_per_eu(1, 1)))
void lstm_fused4(const float* __restrict__ x,     // [B,T] (I=1)
                 const float* __restrict__ Wih0,  // [256]
                 const float* __restrict__ Whh0,  // [256,64]
                 const float* __restrict__ bih0,  // [256]
                 const float* __restrict__ bhh0,  // [256]
                 const float* __restrict__ Wih1,  // [256,64]
                 const float* __restrict__ Whh1,  // [256,64]
                 const float* __restrict__ bih1,  // [256]
                 const float* __restrict__ bhh1,  // [256]
                 const float* __restrict__ Wfc,   // [64]
                 const float* __restrict__ bfc,   // [1]
                 float* __restrict__ out)         // [B]
{
    __shared__ float s_x[NB][TT];     // 8 KB
    __shared__ float s_h0[NB][HH];    // 1 KB
    __shared__ float s_h1[NB][HH];    // 1 KB
    __shared__ float s_g0[NB][256];   // 4 KB
    __shared__ float s_g1[NB][256];   // 4 KB

    const int g  = threadIdx.x;        // gate row 0..255
    const int b0 = blockIdx.x * NB;

    // ---- one-time: per-thread constants + weight rows into registers ----
    const float xw0   = Wih0[g];
    const float bias0 = bih0[g] + bhh0[g];
    const float bias1 = bih1[g] + bhh1[g];

    float4 w0[16], wi1[16], w1[16];    // 192 VGPRs, live across the whole loop
    {
        const float4* p0 = (const float4*)(Whh0 + g * HH);
        const float4* p1 = (const float4*)(Wih1 + g * HH);
        const float4* p2 = (const float4*)(Whh1 + g * HH);
#pragma unroll
        for (int i = 0; i < 16; ++i) {
            w0[i]  = p0[i];
            wi1[i] = p1[i];
            w1[i]  = p2[i];
        }
    }

    // stage x rows (coalesced): NB*TT = 2048 floats / 256 threads = 8 each
#pragma unroll
    for (int k = 0; k < (NB * TT) / 256; ++k) {
        int idx = g + 256 * k;
        int nb  = idx >> 9;       // / TT
        int pos = idx & (TT - 1);
        s_x[nb][pos] = x[(b0 + nb) * TT + pos];
    }

    // zero initial hidden state (NB*HH = 256 floats per array)
    (&s_h0[0][0])[g] = 0.0f;
    (&s_h1[0][0])[g] = 0.0f;

    // cell states: thread g owns layer0 unit (g&63) of batch (g>>6)  -> c0
    //                      and layer1 unit (g&63) of batch (g>>6)  -> c1
    float c0 = 0.0f;
    float c1 = 0.0f;
    const int unb = g >> 6;
    const int uj  = g & 63;

    __syncthreads();

    for (int s = 0; s <= TT; ++s) {
        // ---- phase 1 (all 256 threads): gate matvecs for both layers ----
        // layer0 gates for timestep s (uses h0[s-1]);
        // layer1 gates for timestep s-1 (uses h1[s-2] recurrent + h0[s-1] in).
        {
            const int xs = (s < TT) ? s : (TT - 1);  // s==TT layer0 discarded
            float acc0[NB], acc1[NB];
#pragma unroll
            for (int nb = 0; nb < NB; ++nb) {
                acc0[nb] = fmaf(xw0, s_x[nb][xs], bias0);
                acc1[nb] = bias1;
            }
#pragma unroll
            for (int i = 0; i < 16; ++i) {
#pragma unroll
                for (int nb = 0; nb < NB; ++nb) {
                    const float4 h0q = ((const float4*)s_h0[nb])[i];
                    const float4 h1q = ((const float4*)s_h1[nb])[i];
                    acc0[nb] = fmaf(w0[i].x,  h0q.x, acc0[nb]);
                    acc0[nb] = fmaf(w0[i].y,  h0q.y, acc0[nb]);
                    acc0[nb] = fmaf(w0[i].z,  h0q.z, acc0[nb]);
                    acc0[nb] = fmaf(w0[i].w,  h0q.w, acc0[nb]);
                    acc1[nb] = fmaf(wi1[i].x, h0q.x, acc1[nb]);
                    acc1[nb] = fmaf(wi1[i].y, h0q.y, acc1[nb]);
                    acc1[nb] = fmaf(wi1[i].z, h0q.z, acc1[nb]);
                    acc1[nb] = fmaf(wi1[i].w, h0q.w, acc1[nb]);
                    acc1[nb] = fmaf(w1[i].x,  h1q.x, acc1[nb]);
                    acc1[nb] = fmaf(w1[i].y,  h1q.y, acc1[nb]);
                    acc1[nb] = fmaf(w1[i].z,  h1q.z, acc1[nb]);
                    acc1[nb] = fmaf(w1[i].w,  h1q.w, acc1[nb]);
                }
            }
#pragma unroll
            for (int nb = 0; nb < NB; ++nb) {
                s_g0[nb][g] = acc0[nb];
                s_g1[nb][g] = acc1[nb];
            }
        }
        __syncthreads();

        // ---- phase 2: unit updates, all 256 threads (one unit per layer) ----
        // layer 0, timestep s (skip at s==TT)
        if (s < TT) {
            float i_ = sigmoidf_(s_g0[unb][uj]);
            float f_ = sigmoidf_(s_g0[unb][uj + 64]);
            float g_ = tanhf_(s_g0[unb][uj + 128]);
            float o_ = sigmoidf_(s_g0[unb][uj + 192]);
            c0 = fmaf(f_, c0, i_ * g_);
            s_h0[unb][uj] = o_ * tanhf_(c0);
        }
        // layer 1, timestep s-1 (skip at s==0)
        if (s >= 1) {
            float i_ = sigmoidf_(s_g1[unb][uj]);
            float f_ = sigmoidf_(s_g1[unb][uj + 64]);
            float g_ = tanhf_(s_g1[unb][uj + 128]);
            float o_ = sigmoidf_(s_g1[unb][uj + 192]);
            c1 = fmaf(f_, c1, i_ * g_);
            s_h1[unb][uj] = o_ * tanhf_(c1);
        }
        __syncthreads();
    }

    // ---- epilogue: out[b0+nb] = h1_last . Wfc + bfc ----
    // wave w (= g>>6) reduces batch nb=w across its 64 lanes
    {
        float v = s_h1[unb][uj] * Wfc[uj];
#pragma unroll
        for (int off = 32; off > 0; off >>= 1) {
            v += __shfl_down(v, off);
        }
        if (uj == 0) out[b0 + unb] = v + bfc[0];
    }
}

extern "C" void kernel_launch(void* const* d_in, const int* in_sizes, int n_in,
                              void* d_out, int out_size, void* d_ws, size_t ws_size,
                              hipStream_t stream) {
    const float* x    = (const float*)d_in[0];
    const float* Wih0 = (const float*)d_in[1];
    const float* Whh0 = (const float*)d_in[2];
    const float* bih0 = (const float*)d_in[3];
    const float* bhh0 = (const float*)d_in[4];
    const float* Wih1 = (const float*)d_in[5];
    const float* Whh1 = (const float*)d_in[6];
    const float* bih1 = (const float*)d_in[7];
    const float* bhh1 = (const float*)d_in[8];
    const float* Wfc  = (const float*)d_in[9];
    const float* bfc  = (const float*)d_in[10];
    float* out = (float*)d_out;

    lstm_fused4<<<dim3(BB / NB), dim3(256), 0, stream>>>(
        x, Wih0, Whh0, bih0, bhh0, Wih1, Whh1, bih1, bhh1, Wfc, bfc, out);
}

// Round 5
// 1091.152 us; speedup vs baseline: 4.5422x; 1.5679x over previous
//
#include <hip/hip_runtime.h>

#define BB  1024
#define TT  512
#define HH  64
#define NBB 16          // batches per block; grid = 64 blocks
#define PAD 72          // padded bf16 row stride for h arrays (breaks bank conflicts)

typedef __attribute__((ext_vector_type(8))) short  short8;   // 8 bf16 = 4 VGPR (MFMA A/B frag)
typedef __attribute__((ext_vector_type(4))) short  short4v;  // 4 bf16 = 8 B
typedef __attribute__((ext_vector_type(4))) float  f32x4;    // MFMA C/D frag

__device__ __forceinline__ unsigned short f2bf(float f) {
    unsigned u = __float_as_uint(f);
    u += 0x7FFF + ((u >> 16) & 1);          // round-to-nearest-even
    return (unsigned short)(u >> 16);
}
__device__ __forceinline__ float bf2f(unsigned short s) {
    return __uint_as_float(((unsigned)s) << 16);
}
__device__ __forceinline__ float sigm(float v) { return 1.0f / (1.0f + __expf(-v)); }
__device__ __forceinline__ float tanh_(float v) { return fmaf(2.0f, sigm(2.0f * v), -1.0f); }

// Split-bf16 MFMA fused 2-layer LSTM.
//  - W split W = Wh + Wl (bf16 hi/lo), h split likewise each step.
//  - gates = Wh.hh + Wh.hl + Wl.hh  (Wl.hl dropped, ~2^-18 relative).
//  - 8 waves: lay = wid&1 (balances 24 vs 48 MFMA across SIMDs), grp = wid>>1.
//    Wave owns gate tiles {grp, grp+4, grp+8, grp+12} of its layer -> all 4
//    gates of units [16*grp,16*grp+16) stay in its C-fragments (no LDS gates).
//  - Layer1 runs one step behind layer0; h hi/lo double-buffered by parity ->
//    ONE barrier per step.
__global__ __launch_bounds__(512)
__attribute__((amdgpu_waves_per_eu(2, 2)))
void lstm_mfma(const float* __restrict__ x,     // [B,T] (I=1)
               const float* __restrict__ Wih0,  // [256]
               const float* __restrict__ Whh0,  // [256,64]
               const float* __restrict__ bih0,  // [256]
               const float* __restrict__ bhh0,  // [256]
               const float* __restrict__ Wih1,  // [256,64]
               const float* __restrict__ Whh1,  // [256,64]
               const float* __restrict__ bih1,  // [256]
               const float* __restrict__ bhh1,  // [256]
               const float* __restrict__ Wfc,   // [64]
               const float* __restrict__ bfc,   // [1]
               float* __restrict__ out)         // [B]
{
    __shared__ __align__(16) float          s_x[NBB][TT + 1];     // 32.8 KB
    __shared__ __align__(16) unsigned short s_h0h[2][NBB][PAD];   // 4.5 KB
    __shared__ __align__(16) unsigned short s_h0l[2][NBB][PAD];
    __shared__ __align__(16) unsigned short s_h1h[2][NBB][PAD];
    __shared__ __align__(16) unsigned short s_h1l[2][NBB][PAD];
    __shared__ __align__(16) float          s_h1f[NBB][68];       // 4.3 KB

    const int tid  = threadIdx.x;
    const int lane = tid & 63;
    const int wid  = tid >> 6;
    const int lay  = wid & 1;    // 0: layer0 wave, 1: layer1 wave
    const int G    = wid >> 1;   // unit group 0..3 (units 16G..16G+15)
    const int q    = lane >> 4;  // quad 0..3
    const int n16  = lane & 15;  // batch column within tile
    const int b0   = blockIdx.x * NBB;

    // ---- one-time: A fragments (hi/lo split) + per-lane bias/xw ----
    // A-frag layout (16x16x32): lane holds A[m = lane&15][k = 8q + j], j=0..7.
    short8 Ah[4][4], Al[4][4];
    float  bias[4][4], xw[4][4];

    for (int gi = 0; gi < 4; ++gi) {
        // C/D row (4q+r) -> gate row for bias / x-term
        for (int r = 0; r < 4; ++r) {
            const int row = 64 * gi + 16 * G + 4 * q + r;
            if (lay == 0) { bias[gi][r] = bih0[row] + bhh0[row]; xw[gi][r] = Wih0[row]; }
            else          { bias[gi][r] = bih1[row] + bhh1[row]; xw[gi][r] = 0.0f; }
        }
        const int rowA = 64 * gi + 16 * G + n16;
        const int KT   = lay ? 4 : 2;
        for (int kt = 0; kt < 4; ++kt) {
            if (kt < KT) {
                const float* src;
                if (lay == 0)    src = Whh0 + rowA * 64 + 32 * kt + 8 * q;
                else if (kt < 2) src = Wih1 + rowA * 64 + 32 * kt + 8 * q;
                else             src = Whh1 + rowA * 64 + 32 * (kt - 2) + 8 * q;
                short8 hv, lv;
                for (int j = 0; j < 8; ++j) {
                    const float w = src[j];
                    const unsigned short hs = f2bf(w);
                    const unsigned short ls = f2bf(w - bf2f(hs));
                    hv[j] = (short)hs;
                    lv[j] = (short)ls;
                }
                Ah[gi][kt] = hv;
                Al[gi][kt] = lv;
            }
        }
    }

    // ---- stage x (coalesced) + zero h buffers ----
    for (int i = tid; i < NBB * TT; i += 512) {
        const int nb = i >> 9, pos = i & (TT - 1);
        s_x[nb][pos] = x[(b0 + nb) * TT + pos];
    }
    for (int i = tid; i < 2 * NBB * PAD / 2; i += 512) {   // 1152 dwords per array
        ((unsigned*)s_h0h)[i] = 0u; ((unsigned*)s_h0l)[i] = 0u;
        ((unsigned*)s_h1h)[i] = 0u; ((unsigned*)s_h1l)[i] = 0u;
    }

    float c[4] = {0.0f, 0.0f, 0.0f, 0.0f};   // cell state for this wave's units

    __syncthreads();

    for (int s = 0; s <= TT; ++s) {
        const int p = (s & 1) ^ 1;   // read parity
        const int w = s & 1;         // write parity
        f32x4 acc[4];

        if (lay == 0) {
            // ---- layer0 compute, timestep s: gates0 = Wih0*x + b + Whh0*h0[s-1]
            const float xv = s_x[n16][(s < TT) ? s : (TT - 1)];
            short8 Bh[2], Bl[2];
#pragma unroll
            for (int kt = 0; kt < 2; ++kt) {
                Bh[kt] = *(const short8*)&s_h0h[p][n16][32 * kt + 8 * q];
                Bl[kt] = *(const short8*)&s_h0l[p][n16][32 * kt + 8 * q];
            }
#pragma unroll
            for (int gi = 0; gi < 4; ++gi) {
                f32x4 a;
#pragma unroll
                for (int r = 0; r < 4; ++r) a[r] = fmaf(xw[gi][r], xv, bias[gi][r]);
#pragma unroll
                for (int kt = 0; kt < 2; ++kt) {
                    a = __builtin_amdgcn_mfma_f32_16x16x32_bf16(Ah[gi][kt], Bh[kt], a, 0, 0, 0);
                    a = __builtin_amdgcn_mfma_f32_16x16x32_bf16(Ah[gi][kt], Bl[kt], a, 0, 0, 0);
                    a = __builtin_amdgcn_mfma_f32_16x16x32_bf16(Al[gi][kt], Bh[kt], a, 0, 0, 0);
                }
                acc[gi] = a;
            }
            // ---- layer0 update (skip at s == TT) ----
            if (s < TT) {
                short4v vh, vl;
#pragma unroll
                for (int r = 0; r < 4; ++r) {
                    const float i_ = sigm(acc[0][r]);
                    const float f_ = sigm(acc[1][r]);
                    const float g_ = tanh_(acc[2][r]);
                    const float o_ = sigm(acc[3][r]);
                    c[r] = fmaf(f_, c[r], i_ * g_);
                    const float h = o_ * tanh_(c[r]);
                    const unsigned short hs = f2bf(h);
                    const unsigned short lo = f2bf(h - bf2f(hs));
                    vh[r] = (short)hs;
                    vl[r] = (short)lo;
                }
                const int base = 16 * G + 4 * q;
                *(short4v*)&s_h0h[w][n16][base] = vh;
                *(short4v*)&s_h0l[w][n16][base] = vl;
            }
        } else {
            // ---- layer1 compute, timestep s-1: gates1 = Wih1*h0[s-1] + b + Whh1*h1[s-2]
            short8 Bh[4], Bl[4];
#pragma unroll
            for (int kt = 0; kt < 2; ++kt) {
                Bh[kt] = *(const short8*)&s_h0h[p][n16][32 * kt + 8 * q];
                Bl[kt] = *(const short8*)&s_h0l[p][n16][32 * kt + 8 * q];
            }
#pragma unroll
            for (int kt = 0; kt < 2; ++kt) {
                Bh[2 + kt] = *(const short8*)&s_h1h[p][n16][32 * kt + 8 * q];
                Bl[2 + kt] = *(const short8*)&s_h1l[p][n16][32 * kt + 8 * q];
            }
#pragma unroll
            for (int gi = 0; gi < 4; ++gi) {
                f32x4 a;
#pragma unroll
                for (int r = 0; r < 4; ++r) a[r] = bias[gi][r];
#pragma unroll
                for (int kt = 0; kt < 4; ++kt) {
                    a = __builtin_amdgcn_mfma_f32_16x16x32_bf16(Ah[gi][kt], Bh[kt], a, 0, 0, 0);
                    a = __builtin_amdgcn_mfma_f32_16x16x32_bf16(Ah[gi][kt], Bl[kt], a, 0, 0, 0);
                    a = __builtin_amdgcn_mfma_f32_16x16x32_bf16(Al[gi][kt], Bh[kt], a, 0, 0, 0);
                }
                acc[gi] = a;
            }
            // ---- layer1 update for step s-1 (skip at s == 0) ----
            if (s >= 1) {
                short4v vh, vl;
                f32x4 hf;
#pragma unroll
                for (int r = 0; r < 4; ++r) {
                    const float i_ = sigm(acc[0][r]);
                    const float f_ = sigm(acc[1][r]);
                    const float g_ = tanh_(acc[2][r]);
                    const float o_ = sigm(acc[3][r]);
                    c[r] = fmaf(f_, c[r], i_ * g_);
                    const float h = o_ * tanh_(c[r]);
                    const unsigned short hs = f2bf(h);
                    const unsigned short lo = f2bf(h - bf2f(hs));
                    vh[r] = (short)hs;
                    vl[r] = (short)lo;
                    hf[r] = h;
                }
                const int base = 16 * G + 4 * q;
                *(short4v*)&s_h1h[w][n16][base] = vh;
                *(short4v*)&s_h1l[w][n16][base] = vl;
                if (s == TT) *(f32x4*)&s_h1f[n16][base] = hf;  // final h1 for FC
            }
        }
        __syncthreads();
    }

    // ---- epilogue: out[b0+i] = h1_last . Wfc + bfc ----
    if (tid < NBB) {
        float a = bfc[0];
        for (int j = 0; j < HH; ++j) a = fmaf(Wfc[j], s_h1f[tid][j], a);
        out[b0 + tid] = a;
    }
}

extern "C" void kernel_launch(void* const* d_in, const int* in_sizes, int n_in,
                              void* d_out, int out_size, void* d_ws, size_t ws_size,
                              hipStream_t stream) {
    const float* x    = (const float*)d_in[0];
    const float* Wih0 = (const float*)d_in[1];
    const float* Whh0 = (const float*)d_in[2];
    const float* bih0 = (const float*)d_in[3];
    const float* bhh0 = (const float*)d_in[4];
    const float* Wih1 = (const float*)d_in[5];
    const float* Whh1 = (const float*)d_in[6];
    const float* bih1 = (const float*)d_in[7];
    const float* bhh1 = (const float*)d_in[8];
    const float* Wfc  = (const float*)d_in[9];
    const float* bfc  = (const float*)d_in[10];
    float* out = (float*)d_out;

    lstm_mfma<<<dim3(BB / NBB), dim3(512), 0, stream>>>(
        x, Wih0, Whh0, bih0, bhh0, Wih1, Whh1, bih1, bhh1, Wfc, bfc, out);
}